// Round 5
// baseline (2564.837 us; speedup 1.0000x reference)
//
#include <hip/hip_runtime.h>

// GCN critic: 4 layers (128->16->16->16->1), symmetric gcn_norm with self-loops,
// global mean pool. N=100000 nodes, E=6400000 edges.
// R4: two-key counting sort (dst-bucket x src-chunk) -> exact segmented CSR.
// Aggregation gathers z[src] from a 1MB L2-resident chunk window; LDS-private
// accumulators; zero per-edge global atomics.

#define BSHIFT 7
#define BSIZE 128            // nodes per dst bucket
#define CSHIFT 14            // 16384 src nodes per chunk -> 1MB z slice
#define NCHUNK 8             // segments per bucket (src < 131072)
#define NSEG_ALLOC 6400      // >= nbuck*NCHUNK = 782*8 = 6256
#define NSRC_MASK 131071     // 17-bit src
#define BLKB 512
#define CHUNKE 32768         // edges per hist/fill block

static __device__ __forceinline__ float relu_(float v) { return v > 0.f ? v : 0.f; }

// ---- zero segment counters + out ----
__global__ __launch_bounds__(256) void k_zero(int* __restrict__ scnt, float* __restrict__ out, int nseg) {
    int i = blockIdx.x * 256 + threadIdx.x;
    if (i < nseg) scnt[i] = 0;
    if (i == 0) out[0] = 0.0f;
}

static __device__ __forceinline__ int seg_of(int d, int s) {
    return ((d >> BSHIFT) << 3) | ((unsigned)s >> CSHIFT);
}

// ---- pass 1: per-block LDS histogram -> global segment counts ----
__global__ __launch_bounds__(BLKB) void k_hist(const int* __restrict__ src, const int* __restrict__ dst,
                                               int* __restrict__ scnt, int E, int nseg) {
    __shared__ int hist[NSEG_ALLOC];
    const int t = threadIdx.x;
    for (int i = t; i < nseg; i += BLKB) hist[i] = 0;
    __syncthreads();
    const int c0 = blockIdx.x * CHUNKE;
    const int c1 = min(c0 + CHUNKE, E);
    for (int e = c0 + t; e < c1; e += BLKB)
        atomicAdd(&hist[seg_of(dst[e], src[e])], 1);
    __syncthreads();
    for (int i = t; i < nseg; i += BLKB) {
        int h = hist[i];
        if (h) atomicAdd(&scnt[i], h);
    }
}

// ---- exclusive scan of scnt -> rowptr (+cursor copy); one block ----
__global__ __launch_bounds__(1024) void k_scan(const int* __restrict__ scnt, int* __restrict__ rowptr,
                                               int* __restrict__ cursor, int nseg) {
    __shared__ int ps[1024];
    const int t = threadIdx.x;
    int base = t * 8;
    int loc = 0;
    for (int k = 0; k < 8; ++k) { int i = base + k; if (i < nseg) loc += scnt[i]; }
    ps[t] = loc;
    __syncthreads();
    for (int o = 1; o < 1024; o <<= 1) {
        int x = 0;
        if (t >= o) x = ps[t - o];
        __syncthreads();
        ps[t] += x;
        __syncthreads();
    }
    int run = ps[t] - loc;   // exclusive base for this thread's range
    for (int k = 0; k < 8; ++k) {
        int i = base + k;
        if (i < nseg) {
            rowptr[i] = run;
            cursor[i] = run;
            run += scnt[i];
        }
    }
}

// ---- pass 2: fill records. rec = {norm-placeholder w (hi32), dstloc<<17|src (lo32)} ----
__global__ __launch_bounds__(BLKB) void k_fill(const int* __restrict__ src, const int* __restrict__ dst,
                                               const float* __restrict__ w, int* __restrict__ cursor,
                                               long long* __restrict__ ep, int E, int nseg) {
    __shared__ int hist[NSEG_ALLOC];
    __shared__ int cur[NSEG_ALLOC];
    const int t = threadIdx.x;
    for (int i = t; i < nseg; i += BLKB) hist[i] = 0;
    __syncthreads();
    const int c0 = blockIdx.x * CHUNKE;
    const int c1 = min(c0 + CHUNKE, E);
    for (int e = c0 + t; e < c1; e += BLKB)
        atomicAdd(&hist[seg_of(dst[e], src[e])], 1);
    __syncthreads();
    for (int i = t; i < nseg; i += BLKB) {
        int h = hist[i];
        cur[i] = h ? atomicAdd(&cursor[i], h) : 0;   // reserve contiguous range
    }
    __syncthreads();
    for (int e = c0 + t; e < c1; e += BLKB) {
        int d = dst[e], s = src[e];
        int sg = seg_of(d, s);
        int pos = atomicAdd(&cur[sg], 1);
        unsigned meta = ((unsigned)(d & (BSIZE - 1)) << 17) | (unsigned)s;
        ep[pos] = ((long long)__float_as_int(w[e]) << 32) | (long long)meta;
    }
}

// ---- per-bucket degree -> dis = 1/sqrt(deg+1) ----
__global__ __launch_bounds__(256) void k_degdis(const long long* __restrict__ ep, const int* __restrict__ rowptr,
                                                const int* __restrict__ scnt, float* __restrict__ dis, int n) {
    __shared__ float dl[BSIZE];
    const int b = blockIdx.x, t = threadIdx.x;
    if (t < BSIZE) dl[t] = 0.f;
    __syncthreads();
    for (int c = 0; c < NCHUNK; ++c) {
        int sg = (b << 3) | c;
        int start = rowptr[sg], cnt = scnt[sg];
        for (int e = t; e < cnt; e += 256) {
            long long r = ep[start + e];
            atomicAdd(&dl[((unsigned)r) >> 17], __int_as_float((int)(r >> 32)));
        }
    }
    __syncthreads();
    int node = (b << BSHIFT) + t;
    if (t < BSIZE && node < n)
        dis[node] = (float)(1.0 / sqrt((double)(dl[t] + 1.0f)));
}

// ---- transform w -> norm = dis[src]*w*dis[dst] in place ----
__global__ __launch_bounds__(256) void k_norm(long long* __restrict__ ep, const int* __restrict__ rowptr,
                                              const int* __restrict__ scnt, const float* __restrict__ dis, int n) {
    __shared__ float dloc[BSIZE];
    const int b = blockIdx.x, t = threadIdx.x;
    int node = (b << BSHIFT) + t;
    if (t < BSIZE) dloc[t] = (node < n) ? dis[node] : 0.f;
    __syncthreads();
    for (int c = 0; c < NCHUNK; ++c) {
        int sg = (b << 3) | c;
        int start = rowptr[sg], cnt = scnt[sg];
        for (int e = t; e < cnt; e += 256) {
            long long r = ep[start + e];
            unsigned meta = (unsigned)r;
            float nv = dis[meta & NSRC_MASK] * __int_as_float((int)(r >> 32)) * dloc[meta >> 17];
            ep[start + e] = ((long long)__float_as_int(nv) << 32) | (long long)meta;
        }
    }
}

// ---- dense: z = act(xin) @ W ; act = relu(x + bprev) if RELU ----
template<int FI, int FO, bool RELU>
__global__ __launch_bounds__(256) void k_dense(const float* __restrict__ xin, const float* __restrict__ W,
                                               const float* __restrict__ bprev, float* __restrict__ z, int n) {
    constexpr int NPB = 256 / FO;
    constexpr int XP = FI + 1;
    __shared__ float Wl[FI * FO];
    __shared__ float xs[NPB * XP];
    const int t = threadIdx.x;
    for (int i = t; i < FI * FO; i += 256) Wl[i] = W[i];
    const int node0 = blockIdx.x * NPB;
    for (int i = t; i < NPB * FI; i += 256) {
        int r = i / FI, c = i - r * FI;
        int node = node0 + r;
        float v = 0.f;
        if (node < n) {
            v = xin[node * FI + c];
            if constexpr (RELU) v = relu_(v + bprev[c]);
        }
        xs[r * XP + c] = v;
    }
    __syncthreads();
    const int r = t / FO, j = t - r * FO;
    const int node = node0 + r;
    if (node < n) {
        float s = 0.f;
#pragma unroll
        for (int k = 0; k < FI; ++k) s += xs[r * XP + k] * Wl[k * FO + j];
        z[node * FO + j] = s;
    }
}

// ---- aggregation FO=16: one block (512 thr) per bucket; sweep src-chunks in order
// so the z gather window (1MB/chunk) stays L2-resident across all CUs.
__global__ __launch_bounds__(512) void k_agg16(const long long* __restrict__ ep, const int* __restrict__ rowptr,
                                               const int* __restrict__ scnt, const float* __restrict__ dis,
                                               const float* __restrict__ z, float* __restrict__ acc, int n) {
    __shared__ float al[BSIZE * 16];   // 8 KB
    const int b = blockIdx.x, t = threadIdx.x;
    for (int i = t; i < BSIZE * 16; i += 512) al[i] = 0.f;
    __syncthreads();
    const int eo = t >> 4, j = t & 15;   // 32 edge-groups x 16 features
    for (int c = 0; c < NCHUNK; ++c) {
        int sg = (b << 3) | c;
        int start = rowptr[sg], cnt = scnt[sg];
        const long long* p = ep + start;
        int e = eo;
        for (; e + 32 < cnt; e += 64) {   // 2x unrolled: two independent load chains
            long long r0 = p[e], r1 = p[e + 32];
            unsigned m0 = (unsigned)r0, m1 = (unsigned)r1;
            float z0 = z[(m0 & NSRC_MASK) * 16 + j];
            float z1v = z[(m1 & NSRC_MASK) * 16 + j];
            atomicAdd(&al[(m0 >> 17) * 16 + j], z0 * __int_as_float((int)(r0 >> 32)));
            atomicAdd(&al[(m1 >> 17) * 16 + j], z1v * __int_as_float((int)(r1 >> 32)));
        }
        if (e < cnt) {
            long long r0 = p[e];
            unsigned m0 = (unsigned)r0;
            atomicAdd(&al[(m0 >> 17) * 16 + j],
                      z[(m0 & NSRC_MASK) * 16 + j] * __int_as_float((int)(r0 >> 32)));
        }
    }
    __syncthreads();
    for (int i = t; i < BSIZE * 16; i += 512) {
        int node = (b << BSHIFT) + (i >> 4);
        if (node < n) {
            float di = dis[node];
            int jj = i & 15;
            acc[node * 16 + jj] = z[node * 16 + jj] * di * di + al[i];
        }
    }
}

// ---- aggregation FO=1 + final relu+bias+mean, fused ----
__global__ __launch_bounds__(256) void k_agg1(const long long* __restrict__ ep, const int* __restrict__ rowptr,
                                              const int* __restrict__ scnt, const float* __restrict__ dis,
                                              const float* __restrict__ z1, const float* __restrict__ b4,
                                              float* __restrict__ out, int n) {
    __shared__ float al[BSIZE];
    const int b = blockIdx.x, t = threadIdx.x;
    if (t < BSIZE) al[t] = 0.f;
    __syncthreads();
    for (int c = 0; c < NCHUNK; ++c) {
        int sg = (b << 3) | c;
        int start = rowptr[sg], cnt = scnt[sg];
        for (int e = t; e < cnt; e += 256) {
            long long r = ep[start + e];
            unsigned meta = (unsigned)r;
            atomicAdd(&al[meta >> 17], z1[meta & NSRC_MASK] * __int_as_float((int)(r >> 32)));
        }
    }
    __syncthreads();
    int node = (b << BSHIFT) + t;
    float v = 0.f;
    if (t < BSIZE && node < n) {
        float di = dis[node];
        v = relu_(z1[node] * di * di + al[t] + b4[0]);
    }
#pragma unroll
    for (int o = 32; o > 0; o >>= 1) v += __shfl_down(v, o, 64);
    __shared__ float wsum[4];
    if ((t & 63) == 0) wsum[t >> 6] = v;
    __syncthreads();
    if (t == 0) {
        float s = 0.f;
#pragma unroll
        for (int k = 0; k < 4; ++k) s += wsum[k];
        atomicAdd(out, s / (float)n);
    }
}

static inline size_t align_up(size_t x) { return (x + 255) & ~(size_t)255; }

extern "C" void kernel_launch(void* const* d_in, const int* in_sizes, int n_in,
                              void* d_out, int out_size, void* d_ws, size_t ws_size,
                              hipStream_t stream) {
    const float* vf  = (const float*)d_in[0];   // [N,128]
    const int*   edg = (const int*)d_in[1];     // [2,E] int32
    const float* w   = (const float*)d_in[2];   // [E]
    const float* W1  = (const float*)d_in[3];
    const float* b1  = (const float*)d_in[4];
    const float* W2  = (const float*)d_in[5];
    const float* b2  = (const float*)d_in[6];
    const float* W3  = (const float*)d_in[7];
    const float* b3  = (const float*)d_in[8];
    const float* W4  = (const float*)d_in[9];
    const float* b4  = (const float*)d_in[10];
    float* out = (float*)d_out;

    const int n = in_sizes[0] / 128;   // 100000
    const int E = in_sizes[2];         // 6400000
    const int* src = edg;
    const int* dst = edg + E;
    const int nbuck = (n + BSIZE - 1) >> BSHIFT;   // 782
    const int nseg = nbuck << 3;                    // 6256

    char* ws = (char*)d_ws;
    size_t off = 0;
    int*       scnt   = (int*)(ws + off);       off += align_up((size_t)nseg * 4);
    int*       rowptr = (int*)(ws + off);       off += align_up((size_t)nseg * 4);
    int*       cursor = (int*)(ws + off);       off += align_up((size_t)nseg * 4);
    float*     dis    = (float*)(ws + off);     off += align_up((size_t)n * 4);
    long long* ep     = (long long*)(ws + off); off += align_up((size_t)E * 8);
    float*     z      = (float*)(ws + off);     off += align_up((size_t)n * 16 * 4);
    float*     acc    = (float*)(ws + off);     off += align_up((size_t)n * 16 * 4);
    float*     z1     = z;   // layer-4 dense output aliases z (only n floats used)
    (void)ws_size;

    const int gB = (E + CHUNKE - 1) / CHUNKE;            // 196
    const int gD16 = (n + 15) / 16;                      // dense FO=16: 16 nodes/block
    const int gN = (n + 255) / 256;

    k_zero<<<(nseg + 255) / 256, 256, 0, stream>>>(scnt, out, nseg);
    k_hist<<<gB, BLKB, 0, stream>>>(src, dst, scnt, E, nseg);
    k_scan<<<1, 1024, 0, stream>>>(scnt, rowptr, cursor, nseg);
    k_fill<<<gB, BLKB, 0, stream>>>(src, dst, w, cursor, ep, E, nseg);
    k_degdis<<<nbuck, 256, 0, stream>>>(ep, rowptr, scnt, dis, n);
    k_norm<<<nbuck, 256, 0, stream>>>(ep, rowptr, scnt, dis, n);

    // layer 1: 128 -> 16
    k_dense<128, 16, false><<<gD16, 256, 0, stream>>>(vf, W1, nullptr, z, n);
    k_agg16<<<nbuck, 512, 0, stream>>>(ep, rowptr, scnt, dis, z, acc, n);
    // layer 2: 16 -> 16
    k_dense<16, 16, true><<<gD16, 256, 0, stream>>>(acc, W2, b1, z, n);
    k_agg16<<<nbuck, 512, 0, stream>>>(ep, rowptr, scnt, dis, z, acc, n);
    // layer 3: 16 -> 16
    k_dense<16, 16, true><<<gD16, 256, 0, stream>>>(acc, W3, b2, z, n);
    k_agg16<<<nbuck, 512, 0, stream>>>(ep, rowptr, scnt, dis, z, acc, n);
    // layer 4: 16 -> 1 + aggregation + relu+bias+mean (fused)
    k_dense<16, 1, true><<<gN, 256, 0, stream>>>(acc, W4, b3, z1, n);
    k_agg1<<<nbuck, 256, 0, stream>>>(ep, rowptr, scnt, dis, z1, b4, out, n);
}

// Round 6
// 1054.981 us; speedup vs baseline: 2.4312x; 2.4312x over previous
//
#include <hip/hip_runtime.h>

// GCN critic: 4 layers (128->16->16->16->1), symmetric gcn_norm with self-loops,
// global mean pool. N=100000 nodes, E=6400000 edges.
// R5: exact per-node CSR via two-stage counting sort (bucket dst>>6, then in-LDS
// sort within bucket), register-accumulating per-node-wave aggregation with
// 4-way independent load chains. Zero per-edge global atomics.

#define BSHIFT 6
#define BSIZE 64             // nodes per dst bucket
#define NBUCK_ALLOC 1600     // >= nbuck = ceil(100000/64) = 1563
#define CAPB 4800            // max records per bucket (mean 4096, sigma 64 -> +11 sigma)
#define NSRC_MASK 131071     // 17-bit src (src < 131072)
#define BLKB 512
#define CHUNKE 32768         // edges per hist/fill block

static __device__ __forceinline__ float relu_(float v) { return v > 0.f ? v : 0.f; }

// ---- zero bucket counters + out ----
__global__ __launch_bounds__(256) void k_zero(int* __restrict__ gbcnt, float* __restrict__ out, int nbuck) {
    int i = blockIdx.x * 256 + threadIdx.x;
    if (i < nbuck) gbcnt[i] = 0;
    if (i == 0) out[0] = 0.0f;
}

// ---- stage A pass 1: per-block LDS histogram over dst buckets ----
__global__ __launch_bounds__(BLKB) void k_histA(const int* __restrict__ dst, int* __restrict__ gbcnt,
                                                int E, int nbuck) {
    __shared__ int hist[NBUCK_ALLOC];
    const int t = threadIdx.x;
    for (int i = t; i < nbuck; i += BLKB) hist[i] = 0;
    __syncthreads();
    const int c0 = blockIdx.x * CHUNKE;
    const int c1 = min(c0 + CHUNKE, E);
    for (int e = c0 + t; e < c1; e += BLKB)
        atomicAdd(&hist[dst[e] >> BSHIFT], 1);
    __syncthreads();
    for (int i = t; i < nbuck; i += BLKB) {
        int h = hist[i];
        if (h) atomicAdd(&gbcnt[i], h);
    }
}

// ---- stage A scan: brow (exclusive) + bcur copy; one block ----
__global__ __launch_bounds__(1024) void k_scanA(const int* __restrict__ gbcnt, int* __restrict__ brow,
                                                int* __restrict__ bcur, int nbuck, int E) {
    __shared__ int ps[1024];
    const int t = threadIdx.x;
    int i0 = t * 2, i1 = t * 2 + 1;
    int v0 = (i0 < nbuck) ? gbcnt[i0] : 0;
    int v1 = (i1 < nbuck) ? gbcnt[i1] : 0;
    int loc = v0 + v1;
    ps[t] = loc;
    __syncthreads();
    for (int o = 1; o < 1024; o <<= 1) {
        int x = 0;
        if (t >= o) x = ps[t - o];
        __syncthreads();
        ps[t] += x;
        __syncthreads();
    }
    int run = ps[t] - loc;
    if (i0 < nbuck) { brow[i0] = run; bcur[i0] = run; }
    if (i1 < nbuck) { brow[i1] = run + v0; bcur[i1] = run + v0; }
    if (t == 0) brow[nbuck] = E;
}

// ---- stage A pass 2: fill bucket windows. rec = {w (hi32), dstloc<<17|src (lo32)} ----
__global__ __launch_bounds__(BLKB) void k_fillA(const int* __restrict__ src, const int* __restrict__ dst,
                                                const float* __restrict__ w, int* __restrict__ bcur,
                                                long long* __restrict__ ep, int E, int nbuck) {
    __shared__ int hist[NBUCK_ALLOC];
    __shared__ int cur[NBUCK_ALLOC];
    const int t = threadIdx.x;
    for (int i = t; i < nbuck; i += BLKB) hist[i] = 0;
    __syncthreads();
    const int c0 = blockIdx.x * CHUNKE;
    const int c1 = min(c0 + CHUNKE, E);
    for (int e = c0 + t; e < c1; e += BLKB)
        atomicAdd(&hist[dst[e] >> BSHIFT], 1);
    __syncthreads();
    for (int i = t; i < nbuck; i += BLKB) {
        int h = hist[i];
        cur[i] = h ? atomicAdd(&bcur[i], h) : 0;   // reserve contiguous range
    }
    __syncthreads();
    for (int e = c0 + t; e < c1; e += BLKB) {
        int d = dst[e], s = src[e];
        int b = d >> BSHIFT;
        int pos = atomicAdd(&cur[b], 1);
        unsigned meta = ((unsigned)(d & (BSIZE - 1)) << 17) | (unsigned)s;
        ep[pos] = ((long long)__float_as_int(w[e]) << 32) | (long long)meta;
    }
}

// ---- stage B: in-bucket sort by dstloc (in place, via LDS staging) + deg/dis + rowptr2 ----
__global__ __launch_bounds__(BLKB) void k_sortB(long long* __restrict__ ep, const int* __restrict__ brow,
                                                float* __restrict__ dis, int* __restrict__ rowptr2, int n) {
    __shared__ long long stg[CAPB];        // 38.4 KB
    __shared__ int hist[BSIZE];
    __shared__ int excl[BSIZE];
    __shared__ int cur[BSIZE];
    __shared__ float degl[BSIZE];
    const int b = blockIdx.x, t = threadIdx.x;
    if (t < BSIZE) { hist[t] = 0; degl[t] = 0.f; }
    __syncthreads();
    const int base = brow[b];
    const int cnt = brow[b + 1] - base;
    // pass 1: histogram + weighted degree
    for (int e = t; e < cnt; e += BLKB) {
        long long r = ep[base + e];
        int dl = ((unsigned)r) >> 17;
        atomicAdd(&hist[dl], 1);
        atomicAdd(&degl[dl], __int_as_float((int)(r >> 32)));
    }
    __syncthreads();
    if (t == 0) {
        int run = 0;
        for (int k = 0; k < BSIZE; ++k) { excl[k] = run; run += hist[k]; }
    }
    __syncthreads();
    if (t < BSIZE) {
        cur[t] = excl[t];
        int node = (b << BSHIFT) + t;
        if (node < n) {
            dis[node] = (float)(1.0 / sqrt((double)(degl[t] + 1.0f)));   // +1 self-loop
            rowptr2[node] = base + excl[t];
            if (node == n - 1) rowptr2[n] = base + excl[t] + hist[t];
        }
    }
    __syncthreads();
    // pass 2: scatter into LDS at sorted position
    for (int e = t; e < cnt; e += BLKB) {
        long long r = ep[base + e];
        int dl = ((unsigned)r) >> 17;
        int pos = atomicAdd(&cur[dl], 1);
        if (pos < CAPB) stg[pos] = r;
    }
    __syncthreads();
    // write back coalesced (in place)
    const int m = min(cnt, CAPB);
    for (int i = t; i < m; i += BLKB) ep[base + i] = stg[i];
}

// ---- norm: w -> dis[src]*w*dis[dst] in place (per bucket) ----
__global__ __launch_bounds__(BLKB) void k_norm(long long* __restrict__ ep, const int* __restrict__ brow,
                                               const float* __restrict__ dis, int n) {
    __shared__ float dloc[BSIZE];
    const int b = blockIdx.x, t = threadIdx.x;
    int node = (b << BSHIFT) + (t & (BSIZE - 1));
    if (t < BSIZE) dloc[t] = (node < n) ? dis[node] : 0.f;
    __syncthreads();
    const int base = brow[b];
    const int cnt = brow[b + 1] - base;
    for (int e = t; e < cnt; e += BLKB) {
        long long r = ep[base + e];
        unsigned meta = (unsigned)r;
        float nv = dis[meta & NSRC_MASK] * __int_as_float((int)(r >> 32)) * dloc[meta >> 17];
        ep[base + e] = ((long long)__float_as_int(nv) << 32) | (long long)meta;
    }
}

// ---- dense: z = act(xin) @ W ; act = relu(x + bprev) if RELU ----
template<int FI, int FO, bool RELU>
__global__ __launch_bounds__(256) void k_dense(const float* __restrict__ xin, const float* __restrict__ W,
                                               const float* __restrict__ bprev, float* __restrict__ z, int n) {
    constexpr int NPB = 256 / FO;
    constexpr int XP = FI + 1;
    __shared__ float Wl[FI * FO];
    __shared__ float xs[NPB * XP];
    const int t = threadIdx.x;
    for (int i = t; i < FI * FO; i += 256) Wl[i] = W[i];
    const int node0 = blockIdx.x * NPB;
    for (int i = t; i < NPB * FI; i += 256) {
        int r = i / FI, c = i - r * FI;
        int node = node0 + r;
        float v = 0.f;
        if (node < n) {
            v = xin[node * FI + c];
            if constexpr (RELU) v = relu_(v + bprev[c]);
        }
        xs[r * XP + c] = v;
    }
    __syncthreads();
    const int r = t / FO, j = t - r * FO;
    const int node = node0 + r;
    if (node < n) {
        float s = 0.f;
#pragma unroll
        for (int k = 0; k < FI; ++k) s += xs[r * XP + k] * Wl[k * FO + j];
        z[node * FO + j] = s;
    }
}

// ---- aggregation FO=16: one wave per node, register accum, 4 independent load chains ----
__global__ __launch_bounds__(256) void k_agg16(const long long* __restrict__ ep, const int* __restrict__ rowptr2,
                                               const float* __restrict__ dis, const float* __restrict__ z,
                                               float* __restrict__ acc, int n) {
    const int wv = (blockIdx.x * 256 + threadIdx.x) >> 6;   // node
    if (wv >= n) return;
    const int lane = threadIdx.x & 63;
    const int j = lane & 15, g = lane >> 4;
    const int base = rowptr2[wv], end = rowptr2[wv + 1];
    float s = 0.f;
    int e = base + g;
    for (; e + 12 < end; e += 16) {     // 4 independent rec->z chains
        long long r0 = ep[e], r1 = ep[e + 4], r2 = ep[e + 8], r3 = ep[e + 12];
        float z0 = z[(((unsigned)r0) & NSRC_MASK) * 16 + j];
        float z1v = z[(((unsigned)r1) & NSRC_MASK) * 16 + j];
        float z2 = z[(((unsigned)r2) & NSRC_MASK) * 16 + j];
        float z3 = z[(((unsigned)r3) & NSRC_MASK) * 16 + j];
        s += z0 * __int_as_float((int)(r0 >> 32));
        s += z1v * __int_as_float((int)(r1 >> 32));
        s += z2 * __int_as_float((int)(r2 >> 32));
        s += z3 * __int_as_float((int)(r3 >> 32));
    }
    for (; e < end; e += 4) {
        long long r0 = ep[e];
        s += z[(((unsigned)r0) & NSRC_MASK) * 16 + j] * __int_as_float((int)(r0 >> 32));
    }
    s += __shfl_xor(s, 16, 64);
    s += __shfl_xor(s, 32, 64);
    if (g == 0) {
        float di = dis[wv];
        acc[wv * 16 + j] = z[wv * 16 + j] * di * di + s;
    }
}

// ---- aggregation FO=1 + final relu+bias+mean, fused ----
__global__ __launch_bounds__(256) void k_agg1(const long long* __restrict__ ep, const int* __restrict__ rowptr2,
                                              const float* __restrict__ dis, const float* __restrict__ z1,
                                              const float* __restrict__ b4, float* __restrict__ out, int n) {
    const int t = threadIdx.x;
    const int wv = (blockIdx.x * 256 + t) >> 6;
    const int lane = t & 63;
    float v = 0.f;
    if (wv < n) {
        const int base = rowptr2[wv], end = rowptr2[wv + 1];
        float s = 0.f;
        for (int e = base + lane; e < end; e += 64) {
            long long r = ep[e];
            s += z1[((unsigned)r) & NSRC_MASK] * __int_as_float((int)(r >> 32));
        }
#pragma unroll
        for (int o = 32; o > 0; o >>= 1) s += __shfl_xor(s, o, 64);
        if (lane == 0) {
            float di = dis[wv];
            v = relu_(z1[wv] * di * di + s + b4[0]);
        }
    }
    __shared__ float wsum[4];
    if (lane == 0) wsum[t >> 6] = v;
    __syncthreads();
    if (t == 0) {
        float s = wsum[0] + wsum[1] + wsum[2] + wsum[3];
        atomicAdd(out, s / (float)n);
    }
}

static inline size_t align_up(size_t x) { return (x + 255) & ~(size_t)255; }

extern "C" void kernel_launch(void* const* d_in, const int* in_sizes, int n_in,
                              void* d_out, int out_size, void* d_ws, size_t ws_size,
                              hipStream_t stream) {
    const float* vf  = (const float*)d_in[0];   // [N,128]
    const int*   edg = (const int*)d_in[1];     // [2,E] int32
    const float* w   = (const float*)d_in[2];   // [E]
    const float* W1  = (const float*)d_in[3];
    const float* b1  = (const float*)d_in[4];
    const float* W2  = (const float*)d_in[5];
    const float* b2  = (const float*)d_in[6];
    const float* W3  = (const float*)d_in[7];
    const float* b3  = (const float*)d_in[8];
    const float* W4  = (const float*)d_in[9];
    const float* b4  = (const float*)d_in[10];
    float* out = (float*)d_out;

    const int n = in_sizes[0] / 128;   // 100000
    const int E = in_sizes[2];         // 6400000
    const int* src = edg;
    const int* dst = edg + E;
    const int nbuck = (n + BSIZE - 1) >> BSHIFT;   // 1563

    char* ws = (char*)d_ws;
    size_t off = 0;
    int*       gbcnt   = (int*)(ws + off);       off += align_up((size_t)nbuck * 4);
    int*       brow    = (int*)(ws + off);       off += align_up((size_t)(nbuck + 1) * 4);
    int*       bcur    = (int*)(ws + off);       off += align_up((size_t)nbuck * 4);
    int*       rowptr2 = (int*)(ws + off);       off += align_up((size_t)(n + 1) * 4);
    float*     dis     = (float*)(ws + off);     off += align_up((size_t)n * 4);
    long long* ep      = (long long*)(ws + off); off += align_up((size_t)E * 8);
    float*     z       = (float*)(ws + off);     off += align_up((size_t)n * 16 * 4);
    float*     acc     = (float*)(ws + off);     off += align_up((size_t)n * 16 * 4);
    float*     z1      = z;   // layer-4 dense output aliases z (only n floats used)
    (void)ws_size;

    const int gB = (E + CHUNKE - 1) / CHUNKE;            // 196
    const int gD16 = (n + 15) / 16;                      // dense FO=16: 16 nodes/block
    const int gN = (n + 255) / 256;
    const int gW = (n + 3) / 4;                          // wave-per-node kernels

    k_zero<<<(nbuck + 255) / 256, 256, 0, stream>>>(gbcnt, out, nbuck);
    k_histA<<<gB, BLKB, 0, stream>>>(dst, gbcnt, E, nbuck);
    k_scanA<<<1, 1024, 0, stream>>>(gbcnt, brow, bcur, nbuck, E);
    k_fillA<<<gB, BLKB, 0, stream>>>(src, dst, w, bcur, ep, E, nbuck);
    k_sortB<<<nbuck, BLKB, 0, stream>>>(ep, brow, dis, rowptr2, n);
    k_norm<<<nbuck, BLKB, 0, stream>>>(ep, brow, dis, n);

    // layer 1: 128 -> 16
    k_dense<128, 16, false><<<gD16, 256, 0, stream>>>(vf, W1, nullptr, z, n);
    k_agg16<<<gW, 256, 0, stream>>>(ep, rowptr2, dis, z, acc, n);
    // layer 2: 16 -> 16
    k_dense<16, 16, true><<<gD16, 256, 0, stream>>>(acc, W2, b1, z, n);
    k_agg16<<<gW, 256, 0, stream>>>(ep, rowptr2, dis, z, acc, n);
    // layer 3: 16 -> 16
    k_dense<16, 16, true><<<gD16, 256, 0, stream>>>(acc, W3, b2, z, n);
    k_agg16<<<gW, 256, 0, stream>>>(ep, rowptr2, dis, z, acc, n);
    // layer 4: 16 -> 1 + aggregation + relu+bias+mean (fused)
    k_dense<16, 1, true><<<gN, 256, 0, stream>>>(acc, W4, b3, z1, n);
    k_agg1<<<gW, 256, 0, stream>>>(ep, rowptr2, dis, z1, b4, out, n);
}

// Round 7
// 734.231 us; speedup vs baseline: 3.4932x; 1.4369x over previous
//
#include <hip/hip_runtime.h>

// GCN critic: 4 layers (128->16->16->16->1), symmetric gcn_norm with self-loops,
// global mean pool. N=100000 nodes, E=6400000 edges.
// R6: R5 structure, plus: (a) k_agg1 writes per-block partials + k_final single
// block reduce (kills 25k same-address atomics, was 322us); (b) k_norm deleted --
// dense kernels write zs = dis*z, aggregation multiplies by dis[dst] in epilogue.

#define BSHIFT 6
#define BSIZE 64             // nodes per dst bucket
#define NBUCK_ALLOC 1600     // >= nbuck = ceil(100000/64) = 1563
#define CAPB 4800            // max records per bucket (mean 4096, sigma 64 -> +11 sigma)
#define NSRC_MASK 131071     // 17-bit src (src < 131072)
#define BLKB 512
#define CHUNKE 32768         // edges per hist/fill block

static __device__ __forceinline__ float relu_(float v) { return v > 0.f ? v : 0.f; }

// ---- zero bucket counters ----
__global__ __launch_bounds__(256) void k_zero(int* __restrict__ gbcnt, int nbuck) {
    int i = blockIdx.x * 256 + threadIdx.x;
    if (i < nbuck) gbcnt[i] = 0;
}

// ---- stage A pass 1: per-block LDS histogram over dst buckets ----
__global__ __launch_bounds__(BLKB) void k_histA(const int* __restrict__ dst, int* __restrict__ gbcnt,
                                                int E, int nbuck) {
    __shared__ int hist[NBUCK_ALLOC];
    const int t = threadIdx.x;
    for (int i = t; i < nbuck; i += BLKB) hist[i] = 0;
    __syncthreads();
    const int c0 = blockIdx.x * CHUNKE;
    const int c1 = min(c0 + CHUNKE, E);
    for (int e = c0 + t; e < c1; e += BLKB)
        atomicAdd(&hist[dst[e] >> BSHIFT], 1);
    __syncthreads();
    for (int i = t; i < nbuck; i += BLKB) {
        int h = hist[i];
        if (h) atomicAdd(&gbcnt[i], h);
    }
}

// ---- stage A scan: brow (exclusive) + bcur copy; one block ----
__global__ __launch_bounds__(1024) void k_scanA(const int* __restrict__ gbcnt, int* __restrict__ brow,
                                                int* __restrict__ bcur, int nbuck, int E) {
    __shared__ int ps[1024];
    const int t = threadIdx.x;
    int i0 = t * 2, i1 = t * 2 + 1;
    int v0 = (i0 < nbuck) ? gbcnt[i0] : 0;
    int v1 = (i1 < nbuck) ? gbcnt[i1] : 0;
    int loc = v0 + v1;
    ps[t] = loc;
    __syncthreads();
    for (int o = 1; o < 1024; o <<= 1) {
        int x = 0;
        if (t >= o) x = ps[t - o];
        __syncthreads();
        ps[t] += x;
        __syncthreads();
    }
    int run = ps[t] - loc;
    if (i0 < nbuck) { brow[i0] = run; bcur[i0] = run; }
    if (i1 < nbuck) { brow[i1] = run + v0; bcur[i1] = run + v0; }
    if (t == 0) brow[nbuck] = E;
}

// ---- stage A pass 2: fill bucket windows. rec = {w (hi32), dstloc<<17|src (lo32)} ----
__global__ __launch_bounds__(BLKB) void k_fillA(const int* __restrict__ src, const int* __restrict__ dst,
                                                const float* __restrict__ w, int* __restrict__ bcur,
                                                long long* __restrict__ ep, int E, int nbuck) {
    __shared__ int hist[NBUCK_ALLOC];
    __shared__ int cur[NBUCK_ALLOC];
    const int t = threadIdx.x;
    for (int i = t; i < nbuck; i += BLKB) hist[i] = 0;
    __syncthreads();
    const int c0 = blockIdx.x * CHUNKE;
    const int c1 = min(c0 + CHUNKE, E);
    for (int e = c0 + t; e < c1; e += BLKB)
        atomicAdd(&hist[dst[e] >> BSHIFT], 1);
    __syncthreads();
    for (int i = t; i < nbuck; i += BLKB) {
        int h = hist[i];
        cur[i] = h ? atomicAdd(&bcur[i], h) : 0;   // reserve contiguous range
    }
    __syncthreads();
    for (int e = c0 + t; e < c1; e += BLKB) {
        int d = dst[e], s = src[e];
        int b = d >> BSHIFT;
        int pos = atomicAdd(&cur[b], 1);
        unsigned meta = ((unsigned)(d & (BSIZE - 1)) << 17) | (unsigned)s;
        ep[pos] = ((long long)__float_as_int(w[e]) << 32) | (long long)meta;
    }
}

// ---- stage B: in-bucket sort by dstloc (in place, via LDS staging) + deg/dis + rowptr2 ----
__global__ __launch_bounds__(BLKB) void k_sortB(long long* __restrict__ ep, const int* __restrict__ brow,
                                                float* __restrict__ dis, int* __restrict__ rowptr2, int n) {
    __shared__ long long stg[CAPB];        // 38.4 KB
    __shared__ int hist[BSIZE];
    __shared__ int excl[BSIZE];
    __shared__ int cur[BSIZE];
    __shared__ float degl[BSIZE];
    const int b = blockIdx.x, t = threadIdx.x;
    if (t < BSIZE) { hist[t] = 0; degl[t] = 0.f; }
    __syncthreads();
    const int base = brow[b];
    const int cnt = brow[b + 1] - base;
    // pass 1: histogram + weighted degree
    for (int e = t; e < cnt; e += BLKB) {
        long long r = ep[base + e];
        int dl = ((unsigned)r) >> 17;
        atomicAdd(&hist[dl], 1);
        atomicAdd(&degl[dl], __int_as_float((int)(r >> 32)));
    }
    __syncthreads();
    if (t == 0) {
        int run = 0;
        for (int k = 0; k < BSIZE; ++k) { excl[k] = run; run += hist[k]; }
    }
    __syncthreads();
    if (t < BSIZE) {
        cur[t] = excl[t];
        int node = (b << BSHIFT) + t;
        if (node < n) {
            dis[node] = (float)(1.0 / sqrt((double)(degl[t] + 1.0f)));   // +1 self-loop
            rowptr2[node] = base + excl[t];
            if (node == n - 1) rowptr2[n] = base + excl[t] + hist[t];
        }
    }
    __syncthreads();
    // pass 2: scatter into LDS at sorted position
    for (int e = t; e < cnt; e += BLKB) {
        long long r = ep[base + e];
        int dl = ((unsigned)r) >> 17;
        int pos = atomicAdd(&cur[dl], 1);
        if (pos < CAPB) stg[pos] = r;
    }
    __syncthreads();
    // write back coalesced (in place)
    const int m = min(cnt, CAPB);
    for (int i = t; i < m; i += BLKB) ep[base + i] = stg[i];
}

// ---- dense: zs = dis * (act(xin) @ W) ; act = relu(x + bprev) if RELU ----
template<int FI, int FO, bool RELU>
__global__ __launch_bounds__(256) void k_dense(const float* __restrict__ xin, const float* __restrict__ W,
                                               const float* __restrict__ bprev, const float* __restrict__ dis,
                                               float* __restrict__ zs, int n) {
    constexpr int NPB = 256 / FO;
    constexpr int XP = FI + 1;
    __shared__ float Wl[FI * FO];
    __shared__ float xs[NPB * XP];
    const int t = threadIdx.x;
    for (int i = t; i < FI * FO; i += 256) Wl[i] = W[i];
    const int node0 = blockIdx.x * NPB;
    for (int i = t; i < NPB * FI; i += 256) {
        int r = i / FI, c = i - r * FI;
        int node = node0 + r;
        float v = 0.f;
        if (node < n) {
            v = xin[node * FI + c];
            if constexpr (RELU) v = relu_(v + bprev[c]);
        }
        xs[r * XP + c] = v;
    }
    __syncthreads();
    const int r = t / FO, j = t - r * FO;
    const int node = node0 + r;
    if (node < n) {
        float s = 0.f;
#pragma unroll
        for (int k = 0; k < FI; ++k) s += xs[r * XP + k] * Wl[k * FO + j];
        zs[node * FO + j] = s * dis[node];
    }
}

// ---- aggregation FO=16: one wave per node, register accum, 4 independent load chains
// acc[d] = dis[d] * ( zs[d] + sum_e w_e * zs[src_e] )
__global__ __launch_bounds__(256) void k_agg16(const long long* __restrict__ ep, const int* __restrict__ rowptr2,
                                               const float* __restrict__ dis, const float* __restrict__ zs,
                                               float* __restrict__ acc, int n) {
    const int wv = (blockIdx.x * 256 + threadIdx.x) >> 6;   // node
    if (wv >= n) return;
    const int lane = threadIdx.x & 63;
    const int j = lane & 15, g = lane >> 4;
    const int base = rowptr2[wv], end = rowptr2[wv + 1];
    float s = 0.f;
    int e = base + g;
    for (; e + 12 < end; e += 16) {     // 4 independent rec->zs chains
        long long r0 = ep[e], r1 = ep[e + 4], r2 = ep[e + 8], r3 = ep[e + 12];
        float z0 = zs[(((unsigned)r0) & NSRC_MASK) * 16 + j];
        float z1v = zs[(((unsigned)r1) & NSRC_MASK) * 16 + j];
        float z2 = zs[(((unsigned)r2) & NSRC_MASK) * 16 + j];
        float z3 = zs[(((unsigned)r3) & NSRC_MASK) * 16 + j];
        s += z0 * __int_as_float((int)(r0 >> 32));
        s += z1v * __int_as_float((int)(r1 >> 32));
        s += z2 * __int_as_float((int)(r2 >> 32));
        s += z3 * __int_as_float((int)(r3 >> 32));
    }
    for (; e < end; e += 4) {
        long long r0 = ep[e];
        s += zs[(((unsigned)r0) & NSRC_MASK) * 16 + j] * __int_as_float((int)(r0 >> 32));
    }
    s += __shfl_xor(s, 16, 64);
    s += __shfl_xor(s, 32, 64);
    if (g == 0) acc[wv * 16 + j] = dis[wv] * (zs[wv * 16 + j] + s);
}

// ---- aggregation FO=1 + relu+bias, per-block partial sums (NO global atomics) ----
__global__ __launch_bounds__(256) void k_agg1(const long long* __restrict__ ep, const int* __restrict__ rowptr2,
                                              const float* __restrict__ dis, const float* __restrict__ zs1,
                                              const float* __restrict__ b4, float* __restrict__ partial, int n) {
    const int t = threadIdx.x;
    const int wv = (blockIdx.x * 256 + t) >> 6;
    const int lane = t & 63;
    float v = 0.f;
    if (wv < n) {
        const int base = rowptr2[wv], end = rowptr2[wv + 1];
        float s = 0.f;
        for (int e = base + lane; e < end; e += 64) {
            long long r = ep[e];
            s += zs1[((unsigned)r) & NSRC_MASK] * __int_as_float((int)(r >> 32));
        }
#pragma unroll
        for (int o = 32; o > 0; o >>= 1) s += __shfl_xor(s, o, 64);
        if (lane == 0) v = relu_(dis[wv] * (zs1[wv] + s) + b4[0]);
    }
    __shared__ float wsum[4];
    if (lane == 0) wsum[t >> 6] = v;
    __syncthreads();
    if (t == 0) partial[blockIdx.x] = wsum[0] + wsum[1] + wsum[2] + wsum[3];
}

// ---- final: out[0] = sum(partial) / n ; one block ----
__global__ __launch_bounds__(1024) void k_final(const float* __restrict__ partial, float* __restrict__ out,
                                                int nb, int n) {
    const int t = threadIdx.x;
    float s = 0.f;
    for (int i = t; i < nb; i += 1024) s += partial[i];
#pragma unroll
    for (int o = 32; o > 0; o >>= 1) s += __shfl_xor(s, o, 64);
    __shared__ float wsum[16];
    if ((t & 63) == 0) wsum[t >> 6] = s;
    __syncthreads();
    if (t == 0) {
        float tot = 0.f;
#pragma unroll
        for (int k = 0; k < 16; ++k) tot += wsum[k];
        out[0] = tot / (float)n;
    }
}

static inline size_t align_up(size_t x) { return (x + 255) & ~(size_t)255; }

extern "C" void kernel_launch(void* const* d_in, const int* in_sizes, int n_in,
                              void* d_out, int out_size, void* d_ws, size_t ws_size,
                              hipStream_t stream) {
    const float* vf  = (const float*)d_in[0];   // [N,128]
    const int*   edg = (const int*)d_in[1];     // [2,E] int32
    const float* w   = (const float*)d_in[2];   // [E]
    const float* W1  = (const float*)d_in[3];
    const float* b1  = (const float*)d_in[4];
    const float* W2  = (const float*)d_in[5];
    const float* b2  = (const float*)d_in[6];
    const float* W3  = (const float*)d_in[7];
    const float* b3  = (const float*)d_in[8];
    const float* W4  = (const float*)d_in[9];
    const float* b4  = (const float*)d_in[10];
    float* out = (float*)d_out;

    const int n = in_sizes[0] / 128;   // 100000
    const int E = in_sizes[2];         // 6400000
    const int* src = edg;
    const int* dst = edg + E;
    const int nbuck = (n + BSIZE - 1) >> BSHIFT;   // 1563

    char* ws = (char*)d_ws;
    size_t off = 0;
    int*       gbcnt   = (int*)(ws + off);       off += align_up((size_t)nbuck * 4);
    int*       brow    = (int*)(ws + off);       off += align_up((size_t)(nbuck + 1) * 4);
    int*       bcur    = (int*)(ws + off);       off += align_up((size_t)nbuck * 4);
    int*       rowptr2 = (int*)(ws + off);       off += align_up((size_t)(n + 1) * 4);
    float*     dis     = (float*)(ws + off);     off += align_up((size_t)n * 4);
    float*     partial = (float*)(ws + off);     off += align_up((size_t)((n + 3) / 4 + 1) * 4);
    long long* ep      = (long long*)(ws + off); off += align_up((size_t)E * 8);
    float*     zsb     = (float*)(ws + off);     off += align_up((size_t)n * 16 * 4);
    float*     acc     = (float*)(ws + off);     off += align_up((size_t)n * 16 * 4);
    float*     zs1     = zsb;   // layer-4 dense output aliases zs (only n floats used)
    (void)ws_size;

    const int gB = (E + CHUNKE - 1) / CHUNKE;            // 196
    const int gD16 = (n + 15) / 16;                      // dense FO=16: 16 nodes/block
    const int gN = (n + 255) / 256;
    const int gW = (n + 3) / 4;                          // wave-per-node kernels

    k_zero<<<(nbuck + 255) / 256, 256, 0, stream>>>(gbcnt, nbuck);
    k_histA<<<gB, BLKB, 0, stream>>>(dst, gbcnt, E, nbuck);
    k_scanA<<<1, 1024, 0, stream>>>(gbcnt, brow, bcur, nbuck, E);
    k_fillA<<<gB, BLKB, 0, stream>>>(src, dst, w, bcur, ep, E, nbuck);
    k_sortB<<<nbuck, BLKB, 0, stream>>>(ep, brow, dis, rowptr2, n);

    // layer 1: 128 -> 16
    k_dense<128, 16, false><<<gD16, 256, 0, stream>>>(vf, W1, nullptr, dis, zsb, n);
    k_agg16<<<gW, 256, 0, stream>>>(ep, rowptr2, dis, zsb, acc, n);
    // layer 2: 16 -> 16
    k_dense<16, 16, true><<<gD16, 256, 0, stream>>>(acc, W2, b1, dis, zsb, n);
    k_agg16<<<gW, 256, 0, stream>>>(ep, rowptr2, dis, zsb, acc, n);
    // layer 3: 16 -> 16
    k_dense<16, 16, true><<<gD16, 256, 0, stream>>>(acc, W3, b2, dis, zsb, n);
    k_agg16<<<gW, 256, 0, stream>>>(ep, rowptr2, dis, zsb, acc, n);
    // layer 4: 16 -> 1, then aggregation + relu+bias into per-block partials
    k_dense<16, 1, true><<<gN, 256, 0, stream>>>(acc, W4, b3, dis, zs1, n);
    k_agg1<<<gW, 256, 0, stream>>>(ep, rowptr2, dis, zs1, b4, partial, n);
    k_final<<<1, 1024, 0, stream>>>(partial, out, gW, n);
}

// Round 8
// 710.326 us; speedup vs baseline: 3.6108x; 1.0337x over previous
//
#include <hip/hip_runtime.h>
#include <hip/hip_fp16.h>

// GCN critic: 4 layers (128->16->16->16->1), symmetric gcn_norm with self-loops,
// global mean pool. N=100000 nodes, E=6400000 edges.
// R7: R6 structure + (a) BSIZE 64->128 (halves fill write-line amplification),
// (b) zs stored fp16 (halves agg16 gather traffic). Accumulation stays fp32.

#define BSHIFT 7
#define BSIZE 128            // nodes per dst bucket
#define NBUCK_ALLOC 800      // >= nbuck = ceil(100000/128) = 782
#define CAPB 9000            // max records per bucket (mean 8192, sigma ~90 -> +9 sigma)
#define NSRC_MASK 131071     // 17-bit src (src < 131072)
#define BLKB 512
#define CHUNKE 32768         // edges per hist/fill block

static __device__ __forceinline__ float relu_(float v) { return v > 0.f ? v : 0.f; }

// ---- zero bucket counters ----
__global__ __launch_bounds__(256) void k_zero(int* __restrict__ gbcnt, int nbuck) {
    int i = blockIdx.x * 256 + threadIdx.x;
    if (i < nbuck) gbcnt[i] = 0;
}

// ---- stage A pass 1: per-block LDS histogram over dst buckets ----
__global__ __launch_bounds__(BLKB) void k_histA(const int* __restrict__ dst, int* __restrict__ gbcnt,
                                                int E, int nbuck) {
    __shared__ int hist[NBUCK_ALLOC];
    const int t = threadIdx.x;
    for (int i = t; i < nbuck; i += BLKB) hist[i] = 0;
    __syncthreads();
    const int c0 = blockIdx.x * CHUNKE;
    const int c1 = min(c0 + CHUNKE, E);
    for (int e = c0 + t; e < c1; e += BLKB)
        atomicAdd(&hist[dst[e] >> BSHIFT], 1);
    __syncthreads();
    for (int i = t; i < nbuck; i += BLKB) {
        int h = hist[i];
        if (h) atomicAdd(&gbcnt[i], h);
    }
}

// ---- stage A scan: brow (exclusive) + bcur copy; one block ----
__global__ __launch_bounds__(1024) void k_scanA(const int* __restrict__ gbcnt, int* __restrict__ brow,
                                                int* __restrict__ bcur, int nbuck, int E) {
    __shared__ int ps[1024];
    const int t = threadIdx.x;
    int i0 = t * 2, i1 = t * 2 + 1;
    int v0 = (i0 < nbuck) ? gbcnt[i0] : 0;
    int v1 = (i1 < nbuck) ? gbcnt[i1] : 0;
    int loc = v0 + v1;
    ps[t] = loc;
    __syncthreads();
    for (int o = 1; o < 1024; o <<= 1) {
        int x = 0;
        if (t >= o) x = ps[t - o];
        __syncthreads();
        ps[t] += x;
        __syncthreads();
    }
    int run = ps[t] - loc;
    if (i0 < nbuck) { brow[i0] = run; bcur[i0] = run; }
    if (i1 < nbuck) { brow[i1] = run + v0; bcur[i1] = run + v0; }
    if (t == 0) brow[nbuck] = E;
}

// ---- stage A pass 2: fill bucket windows. rec = {w (hi32), dstloc<<17|src (lo32)} ----
__global__ __launch_bounds__(BLKB) void k_fillA(const int* __restrict__ src, const int* __restrict__ dst,
                                                const float* __restrict__ w, int* __restrict__ bcur,
                                                long long* __restrict__ ep, int E, int nbuck) {
    __shared__ int hist[NBUCK_ALLOC];
    __shared__ int cur[NBUCK_ALLOC];
    const int t = threadIdx.x;
    for (int i = t; i < nbuck; i += BLKB) hist[i] = 0;
    __syncthreads();
    const int c0 = blockIdx.x * CHUNKE;
    const int c1 = min(c0 + CHUNKE, E);
    for (int e = c0 + t; e < c1; e += BLKB)
        atomicAdd(&hist[dst[e] >> BSHIFT], 1);
    __syncthreads();
    for (int i = t; i < nbuck; i += BLKB) {
        int h = hist[i];
        cur[i] = h ? atomicAdd(&bcur[i], h) : 0;   // reserve contiguous range
    }
    __syncthreads();
    for (int e = c0 + t; e < c1; e += BLKB) {
        int d = dst[e], s = src[e];
        int b = d >> BSHIFT;
        int pos = atomicAdd(&cur[b], 1);
        unsigned meta = ((unsigned)(d & (BSIZE - 1)) << 17) | (unsigned)s;
        ep[pos] = ((long long)__float_as_int(w[e]) << 32) | (long long)meta;
    }
}

// ---- stage B: in-bucket sort by dstloc (in place, via LDS staging) + deg/dis + rowptr2 ----
__global__ __launch_bounds__(BLKB) void k_sortB(long long* __restrict__ ep, const int* __restrict__ brow,
                                                float* __restrict__ dis, int* __restrict__ rowptr2, int n) {
    __shared__ long long stg[CAPB];        // 72 KB
    __shared__ int hist[BSIZE];
    __shared__ int excl[BSIZE];
    __shared__ int cur[BSIZE];
    __shared__ float degl[BSIZE];
    const int b = blockIdx.x, t = threadIdx.x;
    if (t < BSIZE) { hist[t] = 0; degl[t] = 0.f; }
    __syncthreads();
    const int base = brow[b];
    const int cnt = brow[b + 1] - base;
    // pass 1: histogram + weighted degree
    for (int e = t; e < cnt; e += BLKB) {
        long long r = ep[base + e];
        int dl = ((unsigned)r) >> 17;
        atomicAdd(&hist[dl], 1);
        atomicAdd(&degl[dl], __int_as_float((int)(r >> 32)));
    }
    __syncthreads();
    if (t == 0) {
        int run = 0;
        for (int k = 0; k < BSIZE; ++k) { excl[k] = run; run += hist[k]; }
    }
    __syncthreads();
    if (t < BSIZE) {
        cur[t] = excl[t];
        int node = (b << BSHIFT) + t;
        if (node < n) {
            dis[node] = (float)(1.0 / sqrt((double)(degl[t] + 1.0f)));   // +1 self-loop
            rowptr2[node] = base + excl[t];
            if (node == n - 1) rowptr2[n] = base + excl[t] + hist[t];
        }
    }
    __syncthreads();
    // pass 2: scatter into LDS at sorted position
    for (int e = t; e < cnt; e += BLKB) {
        long long r = ep[base + e];
        int dl = ((unsigned)r) >> 17;
        int pos = atomicAdd(&cur[dl], 1);
        if (pos < CAPB) stg[pos] = r;
    }
    __syncthreads();
    // write back coalesced (in place)
    const int m = min(cnt, CAPB);
    for (int i = t; i < m; i += BLKB) ep[base + i] = stg[i];
}

// ---- dense: zs = fp16( dis * (act(xin) @ W) ) ; act = relu(x + bprev) if RELU ----
template<int FI, int FO, bool RELU>
__global__ __launch_bounds__(256) void k_dense(const float* __restrict__ xin, const float* __restrict__ W,
                                               const float* __restrict__ bprev, const float* __restrict__ dis,
                                               __half* __restrict__ zs, int n) {
    constexpr int NPB = 256 / FO;
    constexpr int XP = FI + 1;
    __shared__ float Wl[FI * FO];
    __shared__ float xs[NPB * XP];
    const int t = threadIdx.x;
    for (int i = t; i < FI * FO; i += 256) Wl[i] = W[i];
    const int node0 = blockIdx.x * NPB;
    for (int i = t; i < NPB * FI; i += 256) {
        int r = i / FI, c = i - r * FI;
        int node = node0 + r;
        float v = 0.f;
        if (node < n) {
            v = xin[node * FI + c];
            if constexpr (RELU) v = relu_(v + bprev[c]);
        }
        xs[r * XP + c] = v;
    }
    __syncthreads();
    const int r = t / FO, j = t - r * FO;
    const int node = node0 + r;
    if (node < n) {
        float s = 0.f;
#pragma unroll
        for (int k = 0; k < FI; ++k) s += xs[r * XP + k] * Wl[k * FO + j];
        zs[node * FO + j] = __float2half(s * dis[node]);
    }
}

// ---- aggregation FO=16: one wave per node, register accum, 4 independent load chains
// acc[d] = dis[d] * ( zs[d] + sum_e w_e * zs[src_e] )   (zs fp16, accum fp32)
__global__ __launch_bounds__(256) void k_agg16(const long long* __restrict__ ep, const int* __restrict__ rowptr2,
                                               const float* __restrict__ dis, const __half* __restrict__ zs,
                                               float* __restrict__ acc, int n) {
    const int wv = (blockIdx.x * 256 + threadIdx.x) >> 6;   // node
    if (wv >= n) return;
    const int lane = threadIdx.x & 63;
    const int j = lane & 15, g = lane >> 4;
    const int base = rowptr2[wv], end = rowptr2[wv + 1];
    float s = 0.f;
    int e = base + g;
    for (; e + 12 < end; e += 16) {     // 4 independent rec->zs chains
        long long r0 = ep[e], r1 = ep[e + 4], r2 = ep[e + 8], r3 = ep[e + 12];
        float z0 = __half2float(zs[(((unsigned)r0) & NSRC_MASK) * 16 + j]);
        float z1v = __half2float(zs[(((unsigned)r1) & NSRC_MASK) * 16 + j]);
        float z2 = __half2float(zs[(((unsigned)r2) & NSRC_MASK) * 16 + j]);
        float z3 = __half2float(zs[(((unsigned)r3) & NSRC_MASK) * 16 + j]);
        s += z0 * __int_as_float((int)(r0 >> 32));
        s += z1v * __int_as_float((int)(r1 >> 32));
        s += z2 * __int_as_float((int)(r2 >> 32));
        s += z3 * __int_as_float((int)(r3 >> 32));
    }
    for (; e < end; e += 4) {
        long long r0 = ep[e];
        s += __half2float(zs[(((unsigned)r0) & NSRC_MASK) * 16 + j]) * __int_as_float((int)(r0 >> 32));
    }
    s += __shfl_xor(s, 16, 64);
    s += __shfl_xor(s, 32, 64);
    if (g == 0) acc[wv * 16 + j] = dis[wv] * (__half2float(zs[wv * 16 + j]) + s);
}

// ---- aggregation FO=1 + relu+bias, per-block partial sums (NO global atomics) ----
__global__ __launch_bounds__(256) void k_agg1(const long long* __restrict__ ep, const int* __restrict__ rowptr2,
                                              const float* __restrict__ dis, const __half* __restrict__ zs1,
                                              const float* __restrict__ b4, float* __restrict__ partial, int n) {
    const int t = threadIdx.x;
    const int wv = (blockIdx.x * 256 + t) >> 6;
    const int lane = t & 63;
    float v = 0.f;
    if (wv < n) {
        const int base = rowptr2[wv], end = rowptr2[wv + 1];
        float s = 0.f;
        for (int e = base + lane; e < end; e += 64) {
            long long r = ep[e];
            s += __half2float(zs1[((unsigned)r) & NSRC_MASK]) * __int_as_float((int)(r >> 32));
        }
#pragma unroll
        for (int o = 32; o > 0; o >>= 1) s += __shfl_xor(s, o, 64);
        if (lane == 0) v = relu_(dis[wv] * (__half2float(zs1[wv]) + s) + b4[0]);
    }
    __shared__ float wsum[4];
    if (lane == 0) wsum[t >> 6] = v;
    __syncthreads();
    if (t == 0) partial[blockIdx.x] = wsum[0] + wsum[1] + wsum[2] + wsum[3];
}

// ---- final: out[0] = sum(partial) / n ; one block ----
__global__ __launch_bounds__(1024) void k_final(const float* __restrict__ partial, float* __restrict__ out,
                                                int nb, int n) {
    const int t = threadIdx.x;
    float s = 0.f;
    for (int i = t; i < nb; i += 1024) s += partial[i];
#pragma unroll
    for (int o = 32; o > 0; o >>= 1) s += __shfl_xor(s, o, 64);
    __shared__ float wsum[16];
    if ((t & 63) == 0) wsum[t >> 6] = s;
    __syncthreads();
    if (t == 0) {
        float tot = 0.f;
#pragma unroll
        for (int k = 0; k < 16; ++k) tot += wsum[k];
        out[0] = tot / (float)n;
    }
}

static inline size_t align_up(size_t x) { return (x + 255) & ~(size_t)255; }

extern "C" void kernel_launch(void* const* d_in, const int* in_sizes, int n_in,
                              void* d_out, int out_size, void* d_ws, size_t ws_size,
                              hipStream_t stream) {
    const float* vf  = (const float*)d_in[0];   // [N,128]
    const int*   edg = (const int*)d_in[1];     // [2,E] int32
    const float* w   = (const float*)d_in[2];   // [E]
    const float* W1  = (const float*)d_in[3];
    const float* b1  = (const float*)d_in[4];
    const float* W2  = (const float*)d_in[5];
    const float* b2  = (const float*)d_in[6];
    const float* W3  = (const float*)d_in[7];
    const float* b3  = (const float*)d_in[8];
    const float* W4  = (const float*)d_in[9];
    const float* b4  = (const float*)d_in[10];
    float* out = (float*)d_out;

    const int n = in_sizes[0] / 128;   // 100000
    const int E = in_sizes[2];         // 6400000
    const int* src = edg;
    const int* dst = edg + E;
    const int nbuck = (n + BSIZE - 1) >> BSHIFT;   // 782

    char* ws = (char*)d_ws;
    size_t off = 0;
    int*       gbcnt   = (int*)(ws + off);       off += align_up((size_t)nbuck * 4);
    int*       brow    = (int*)(ws + off);       off += align_up((size_t)(nbuck + 1) * 4);
    int*       bcur    = (int*)(ws + off);       off += align_up((size_t)nbuck * 4);
    int*       rowptr2 = (int*)(ws + off);       off += align_up((size_t)(n + 1) * 4);
    float*     dis     = (float*)(ws + off);     off += align_up((size_t)n * 4);
    float*     partial = (float*)(ws + off);     off += align_up((size_t)((n + 3) / 4 + 1) * 4);
    long long* ep      = (long long*)(ws + off); off += align_up((size_t)E * 8);
    __half*    zsb     = (__half*)(ws + off);    off += align_up((size_t)n * 16 * 2);
    float*     acc     = (float*)(ws + off);     off += align_up((size_t)n * 16 * 4);
    __half*    zs1     = zsb;   // layer-4 dense output aliases zs (only n halves used)
    (void)ws_size;

    const int gB = (E + CHUNKE - 1) / CHUNKE;            // 196
    const int gD16 = (n + 15) / 16;                      // dense FO=16: 16 nodes/block
    const int gN = (n + 255) / 256;
    const int gW = (n + 3) / 4;                          // wave-per-node kernels

    k_zero<<<(nbuck + 255) / 256, 256, 0, stream>>>(gbcnt, nbuck);
    k_histA<<<gB, BLKB, 0, stream>>>(dst, gbcnt, E, nbuck);
    k_scanA<<<1, 1024, 0, stream>>>(gbcnt, brow, bcur, nbuck, E);
    k_fillA<<<gB, BLKB, 0, stream>>>(src, dst, w, bcur, ep, E, nbuck);
    k_sortB<<<nbuck, BLKB, 0, stream>>>(ep, brow, dis, rowptr2, n);

    // layer 1: 128 -> 16
    k_dense<128, 16, false><<<gD16, 256, 0, stream>>>(vf, W1, nullptr, dis, zsb, n);
    k_agg16<<<gW, 256, 0, stream>>>(ep, rowptr2, dis, zsb, acc, n);
    // layer 2: 16 -> 16
    k_dense<16, 16, true><<<gD16, 256, 0, stream>>>(acc, W2, b1, dis, zsb, n);
    k_agg16<<<gW, 256, 0, stream>>>(ep, rowptr2, dis, zsb, acc, n);
    // layer 3: 16 -> 16
    k_dense<16, 16, true><<<gD16, 256, 0, stream>>>(acc, W3, b2, dis, zsb, n);
    k_agg16<<<gW, 256, 0, stream>>>(ep, rowptr2, dis, zsb, acc, n);
    // layer 4: 16 -> 1, then aggregation + relu+bias into per-block partials
    k_dense<16, 1, true><<<gN, 256, 0, stream>>>(acc, W4, b3, dis, zs1, n);
    k_agg1<<<gW, 256, 0, stream>>>(ep, rowptr2, dis, zs1, b4, partial, n);
    k_final<<<1, 1024, 0, stream>>>(partial, out, gW, n);
}